// Round 6
// baseline (11731.553 us; speedup 1.0000x reference)
//
#include <hip/hip_runtime.h>
#include <math.h>

#define NTS 12
#define NND 2048
#define NED 32768
#define XDI 128
#define HDI 256
#define ZDI 32
#define EPSC 1e-10f
#define NH ((size_t)NND * HDI)        // 524288
#define NZ ((size_t)NND * ZDI)        // 65536
#define ZPL ((size_t)NND * 64)        // 131072
#define XSZ ((size_t)NTS * NND * XDI) // 3145728
#define NBLK 1024
#define NWAVE 4096

typedef unsigned short u16;
typedef __bf16 bf16x8 __attribute__((ext_vector_type(8)));
typedef float f32x4 __attribute__((ext_vector_type(4)));

// ---------------- helpers ----------------

__device__ __forceinline__ float lsigf(float x) {
    return fminf(x, 0.f) - log1pf(expf(-fabsf(x)));
}
__device__ __forceinline__ float splus(float v) {
    return fmaxf(v, 0.f) + log1pf(expf(-fabsf(v)));
}
__device__ __forceinline__ u16 f2b(float f) {
    unsigned u = __float_as_uint(f);
    u += 0x7fffu + ((u >> 16) & 1u);
    return (u16)(u >> 16);
}
__device__ __forceinline__ float b2f(u16 b) {
    return __uint_as_float((unsigned)b << 16);
}
__device__ __forceinline__ void f2b2(float v, u16& hi, u16& lo) {
    hi = f2b(v);
    lo = f2b(v - b2f(hi));
}
__device__ __forceinline__ void st_b16(u16* buf, size_t plane, size_t idx, float v) {
    u16 hi, lo;
    f2b2(v, hi, lo);
    buf[idx] = hi;
    buf[plane + idx] = lo;
}
__device__ __forceinline__ void st_b16v4(u16* buf, size_t plane, size_t idx, float4 v) {
    ushort4 h, l;
    f2b2(v.x, h.x, l.x); f2b2(v.y, h.y, l.y);
    f2b2(v.z, h.z, l.z); f2b2(v.w, h.w, l.w);
    *(ushort4*)(buf + idx) = h;
    *(ushort4*)(buf + plane + idx) = l;
}

// grid barrier: generation-counted, device-scope
__device__ __forceinline__ void gbar(int* cnt, int* gen) {
    __syncthreads();
    if (threadIdx.x == 0) {
        __threadfence();
        int g = __hip_atomic_load(gen, __ATOMIC_RELAXED, __HIP_MEMORY_SCOPE_AGENT);
        if (atomicAdd(cnt, 1) == NBLK - 1) {
            atomicExch(cnt, 0);
            __threadfence();
            atomicAdd(gen, 1);
        } else {
            while (__hip_atomic_load(gen, __ATOMIC_RELAXED, __HIP_MEMORY_SCOPE_AGENT) == g)
                __builtin_amdgcn_s_sleep(2);
        }
        __threadfence();
    }
    __syncthreads();
}

// split-bf16 GEMM pass: acc += A(16 rows r*16..)*Bt(16 cols cc*16..), 3-term split
__device__ __forceinline__ void mmpass(f32x4& a0, f32x4& a1, f32x4& a2,
                                       const u16* __restrict__ A, size_t apl,
                                       const u16* __restrict__ Bt, int K,
                                       int r, int cc, int lr, int kg) {
    const u16* ap = A + (size_t)(r * 16 + lr) * K + kg;
    const u16* alp = ap + apl;
    const u16* bp = Bt + (size_t)(cc * 16 + lr) * K + kg;
    const u16* blp = bp + (size_t)K * HDI;
    for (int k0 = 0; k0 < K; k0 += 32) {
        bf16x8 ah = *(const bf16x8*)(ap + k0);
        bf16x8 al = *(const bf16x8*)(alp + k0);
        bf16x8 bh = *(const bf16x8*)(bp + k0);
        bf16x8 bl = *(const bf16x8*)(blp + k0);
        a0 = __builtin_amdgcn_mfma_f32_16x16x32_bf16(ah, bh, a0, 0, 0, 0);
        a1 = __builtin_amdgcn_mfma_f32_16x16x32_bf16(al, bh, a1, 0, 0, 0);
        a2 = __builtin_amdgcn_mfma_f32_16x16x32_bf16(ah, bl, a2, 0, 0, 0);
    }
}

// GIN gather of one 256-wide row (64 lanes, float4/lane)
__device__ __forceinline__ float4 gin_row(const float* __restrict__ in, int n,
                                          const int* __restrict__ offs,
                                          const int* __restrict__ cs, int lane) {
    int e0 = offs[n], e1 = offs[n + 1];
    const float4* base = (const float4*)in;
    float4 a = base[(size_t)n * 64 + lane];
    int j = e0;
    for (; j + 1 < e1; j += 2) {
        float4 v0 = base[(size_t)cs[j] * 64 + lane];
        float4 v1 = base[(size_t)cs[j + 1] * 64 + lane];
        a.x += v0.x + v1.x; a.y += v0.y + v1.y; a.z += v0.z + v1.z; a.w += v0.w + v1.w;
    }
    if (j < e1) {
        float4 v0 = base[(size_t)cs[j] * 64 + lane];
        a.x += v0.x; a.y += v0.y; a.z += v0.z; a.w += v0.w;
    }
    return a;
}

// small GEMM, 2 rows per wave: C[n,0:32] = act(A[n,:]@B + bias)
__device__ __forceinline__ void small2(const float* __restrict__ A, const float* __restrict__ B,
                                       const float* __restrict__ bias, float* __restrict__ C,
                                       int act, int unit, int lane) {
    int n = unit * 2 + (lane >> 5);
    int m = lane & 31;
    float acc = bias ? bias[m] : 0.f;
    const float* ar = A + (size_t)n * HDI;
    for (int k = 0; k < 256; k += 4) {
        float4 a4 = *(const float4*)(ar + k);
        acc += a4.x * B[(k + 0) * 32 + m];
        acc += a4.y * B[(k + 1) * 32 + m];
        acc += a4.z * B[(k + 2) * 32 + m];
        acc += a4.w * B[(k + 3) * 32 + m];
    }
    if (act == 4) acc = splus(acc);
    C[(size_t)n * ZDI + m] = acc;
}

__device__ __forceinline__ void gcn2(const float* __restrict__ xw, const float* __restrict__ b,
                                     float* __restrict__ o, const int* __restrict__ offs,
                                     const int* __restrict__ cs, const float* __restrict__ cw,
                                     const float* __restrict__ dgv, int unit, int lane) {
    int n = unit * 2 + (lane >> 5), m = lane & 31;
    int e0 = offs[n], e1 = offs[n + 1];
    float acc = 0.f;
    for (int j = e0; j < e1; j++) acc += cw[j] * xw[(size_t)cs[j] * ZDI + m];
    o[(size_t)n * ZDI + m] = acc + xw[(size_t)n * ZDI + m] / dgv[n] + b[m];
}

__device__ __forceinline__ void gin32sp(const float* __restrict__ xw, const float* __restrict__ b,
                                        float* __restrict__ o, const int* __restrict__ offs,
                                        const int* __restrict__ cs, int unit, int lane) {
    int n = unit * 2 + (lane >> 5), m = lane & 31;
    int e0 = offs[n], e1 = offs[n + 1];
    float acc = xw[(size_t)n * ZDI + m];
    for (int j = e0; j < e1; j++) acc += xw[(size_t)cs[j] * ZDI + m];
    acc += b[m];
    o[(size_t)n * ZDI + m] = splus(acc);
}

// ---------------- params ----------------

struct PP {
    const float* x; const int* ei; const float* adj; const float* es; const float* ed;
    const float* b_enc; const float* b_pri;
    const float* w_mean; const float* b_mean; const float* w_std; const float* b_std;
    const float* w_pm; const float* b_pm; const float* w_ps; const float* b_ps;
    int* counts; int* cursor; int* offs; int* csrcb; float* csrwb;
    float* deg; float* dinv;
    u16* wt[23]; const float* wsrc[23]; int wk[23];
    u16* xb;
    u16 *phi_xb, *phi_zb, *zcatb, *rhb;
    float *Us, *Ud, *encs, *encd, *pris, *prid;
    float *xwms, *xwmd, *xwss, *xwsd;
    float *means, *meand, *stds, *stdd, *pms, *pss, *pmd, *psd;
    float* zcat;
    float *Pz, *Pr, *Ph, *zG, *R;
    float* h0f[2]; float* h1f[2]; u16* h0b[2]; u16* h1b[2];
    float* out; double* accd;
    int* bcnt; int* bgen;
};

// dec tile (block-level): 64x64 of z_s@z_d^T, store + BCE partials
__device__ void dec_tile(const float* __restrict__ zcat, const float* __restrict__ adj,
                         float* __restrict__ dec, double* __restrict__ acc3,
                         int db, int tid, float* smf) {
    float (*zsS)[68] = (float(*)[68])smf;
    float (*zdS)[68] = (float(*)[68])(smf + 32 * 68);
    const int tx = tid & 15, ty = tid >> 4;
    const int c0 = (db & 31) * 64, r0 = (db >> 5) * 64;
    const int lrow = tid >> 2;
    const int lk = (tid & 3) * 8;

    float4 v0 = *(const float4*)&zcat[(size_t)(r0 + lrow) * 64 + lk];
    float4 v1 = *(const float4*)&zcat[(size_t)(r0 + lrow) * 64 + lk + 4];
    float4 w0 = *(const float4*)&zcat[(size_t)(c0 + lrow) * 64 + 32 + lk];
    float4 w1 = *(const float4*)&zcat[(size_t)(c0 + lrow) * 64 + 32 + lk + 4];
    zsS[lk + 0][lrow] = v0.x; zsS[lk + 1][lrow] = v0.y; zsS[lk + 2][lrow] = v0.z; zsS[lk + 3][lrow] = v0.w;
    zsS[lk + 4][lrow] = v1.x; zsS[lk + 5][lrow] = v1.y; zsS[lk + 6][lrow] = v1.z; zsS[lk + 7][lrow] = v1.w;
    zdS[lk + 0][lrow] = w0.x; zdS[lk + 1][lrow] = w0.y; zdS[lk + 2][lrow] = w0.z; zdS[lk + 3][lrow] = w0.w;
    zdS[lk + 4][lrow] = w1.x; zdS[lk + 5][lrow] = w1.y; zdS[lk + 6][lrow] = w1.z; zdS[lk + 7][lrow] = w1.w;
    __syncthreads();

    float acc[4][4] = {};
#pragma unroll
    for (int k = 0; k < 32; k++) {
        const float4 a4 = *(const float4*)&zsS[k][ty * 4];
        const float4 b4 = *(const float4*)&zdS[k][tx * 4];
        const float aa[4] = {a4.x, a4.y, a4.z, a4.w};
        const float bb[4] = {b4.x, b4.y, b4.z, b4.w};
#pragma unroll
        for (int i = 0; i < 4; i++)
#pragma unroll
            for (int j = 0; j < 4; j++) acc[i][j] += aa[i] * bb[j];
    }

    float asum = 0.f, s1 = 0.f, s2 = 0.f;
#pragma unroll
    for (int i = 0; i < 4; i++) {
        const int r = r0 + ty * 4 + i;
        const float4 av4 = *(const float4*)&adj[(size_t)r * NND + c0 + tx * 4];
        const float av[4] = {av4.x, av4.y, av4.z, av4.w};
        float* drow = &dec[(size_t)r * NND + c0 + tx * 4];
#pragma unroll
        for (int j = 0; j < 4; j++) {
            float d = acc[i][j];
            drow[j] = d;
            float a = av[j];
            asum += a;
            s1 += a * lsigf(d);
            s2 += (1.f - a) * lsigf(-d);
        }
    }
    __syncthreads();
    float* redA = smf;
    float* redB = redA + 256;
    float* redC = redB + 256;
    redA[tid] = asum; redB[tid] = s1; redC[tid] = s2;
    __syncthreads();
    for (int o = 128; o > 0; o >>= 1) {
        if (tid < o) {
            redA[tid] += redA[tid + o];
            redB[tid] += redB[tid + o];
            redC[tid] += redC[tid + o];
        }
        __syncthreads();
    }
    if (tid == 0) {
        atomicAdd(&acc3[0], (double)redA[0]);
        atomicAdd(&acc3[1], (double)redB[0]);
        atomicAdd(&acc3[2], (double)redC[0]);
    }
}

// ---------------- the mega kernel ----------------

__global__ __launch_bounds__(256, 4) void mega(PP p) {
    __shared__ float smf[2 * 32 * 68];   // 17408 B
    const int tid = threadIdx.x, bid = blockIdx.x;
    const int wid = tid >> 6, lane = tid & 63;
    const int wg = bid * 4 + wid;
    const int lr = lane & 15, kg = (lane >> 4) * 8;
    const int c4 = lane * 4;

    // ---- P1: edge count + weight transpose + x convert ----
    for (int u = wg; u < NTS * NED / 64; u += NWAVE) {
        int idx = u * 64 + lane;
        int t = idx >> 15, e = idx & (NED - 1);
        atomicAdd(&p.counts[t * NND + p.ei[(size_t)t * 2 * NED + NED + e]], 1);
    }
    for (int u = wg; u < 23 * 256; u += NWAVE) {
        int m = u >> 8, k = u & 255;
        int K = p.wk[m];
        if (k < K) {
            const float* W = p.wsrc[m];
            u16* D = p.wt[m];
            for (int ci = 0; ci < 4; ci++) {
                int c = lane * 4 + ci;
                float v = W[(size_t)k * HDI + c];
                u16 hi, lo;
                f2b2(v, hi, lo);
                D[(size_t)c * K + k] = hi;
                D[(size_t)K * HDI + (size_t)c * K + k] = lo;
            }
        }
    }
    for (int u = wg; u < (int)(XSZ / 4 / 64); u += NWAVE) {
        size_t i = (size_t)u * 64 + lane;
        float4 v = ((const float4*)p.x)[i];
        ushort4 h, l;
        f2b2(v.x, h.x, l.x); f2b2(v.y, h.y, l.y);
        f2b2(v.z, h.z, l.z); f2b2(v.w, h.w, l.w);
        ((ushort4*)p.xb)[i] = h;
        ((ushort4*)(p.xb + XSZ))[i] = l;
    }
    gbar(p.bcnt, p.bgen);

    // ---- P2: per-t scan (blocks 0..11) ----
    for (int bu = bid; bu < NTS; bu += NBLK) {
        int* tsum = (int*)smf;
        const int* cnt = p.counts + bu * NND;
        int* off = p.offs + bu * (NND + 1);
        float* dg = p.deg + bu * NND;
        float* dv = p.dinv + bu * NND;
        int base = tid * 8;
        int local[8];
        int s = 0;
        for (int i = 0; i < 8; i++) { local[i] = s; s += cnt[base + i]; }
        tsum[tid] = s;
        __syncthreads();
        for (int o = 1; o < 256; o <<= 1) {
            int v = (tid >= o) ? tsum[tid - o] : 0;
            __syncthreads();
            tsum[tid] += v;
            __syncthreads();
        }
        int excl = tsum[tid] - s;
        for (int i = 0; i < 8; i++) off[base + i] = excl + local[i];
        if (tid == 255) off[NND] = excl + s;
        for (int i = 0; i < 8; i++) {
            float d = (float)cnt[base + i] + 1.0f;
            dg[base + i] = d;
            dv[base + i] = 1.0f / sqrtf(d);
        }
        __syncthreads();
    }
    gbar(p.bcnt, p.bgen);

    // ---- P3: CSR fill ----
    for (int u = wg; u < NTS * NED / 64; u += NWAVE) {
        int idx = u * 64 + lane;
        int t = idx >> 15, e = idx & (NED - 1);
        const int* src = p.ei + (size_t)t * 2 * NED;
        const int* dst = src + NED;
        int d = dst[e], s = src[e];
        const int* off_t = p.offs + t * (NND + 1);
        int pos = off_t[d] + atomicAdd(&p.cursor[t * NND + d], 1);
        p.csrcb[(size_t)t * NED + pos] = s;
        p.csrwb[(size_t)t * NED + pos] = p.dinv[t * NND + s] * p.dinv[t * NND + d];
    }
    gbar(p.bcnt, p.bgen);

    // ---- main time loop ----
    for (int t = 0; t < NTS; t++) {
        const int cur = t & 1;
        float* h0 = p.h0f[cur]; float* nh0 = p.h0f[cur ^ 1];
        float* h1 = p.h1f[cur]; float* nh1 = p.h1f[cur ^ 1];
        u16* h0b16 = p.h0b[cur]; u16* nh0b16 = p.h0b[cur ^ 1];
        u16* h1b16 = p.h1b[cur]; u16* nh1b16 = p.h1b[cur ^ 1];
        const int* offs = p.offs + t * (NND + 1);
        const int* cs = p.csrcb + (size_t)t * NED;
        const float* cw = p.csrwb + (size_t)t * NED;
        const float* dgv = p.deg + t * NND;
        const u16* xbt = p.xb + (size_t)t * NND * XDI;
        const float* adj_t = p.adj + (size_t)t * NND * NND;
        float* dec_t = p.out + 2 + (size_t)t * NND * NND;
        const float* es_t = p.es + (size_t)t * NZ;
        const float* ed_t = p.ed + (size_t)t * NZ;
        double* acc3 = &p.accd[1 + 3 * t];

        // S1: phi_x GEMM (bf16-out) || pri_s/pri_d GEMM
        for (int u = wg; u < 6144; u += NWAVE) {
            if (u < 2048) {
                int r = u & 127, cc = u >> 7;
                f32x4 a0 = {}, a1 = {}, a2 = {};
                mmpass(a0, a1, a2, xbt, XSZ, p.wt[0], XDI, r, cc, lr, kg);
                int ccol = cc * 16 + lr, rb = r * 16 + (lane >> 4) * 4;
#pragma unroll
                for (int i = 0; i < 4; i++) {
                    size_t idx = (size_t)(rb + i) * HDI + ccol;
                    st_b16(p.phi_xb, NH, idx, fmaxf(a0[i] + a1[i] + a2[i], 0.f));
                }
            } else {
                int q = u - 2048;
                int o = q >> 11, w = q & 2047;
                int r = w & 127, cc = w >> 7;
                f32x4 a0 = {}, a1 = {}, a2 = {};
                mmpass(a0, a1, a2, h1b16, NH, p.wt[6 + o], HDI, r, cc, lr, kg);
                int ccol = cc * 16 + lr, rb = r * 16 + (lane >> 4) * 4;
                float* C = o ? p.prid : p.pris;
                const float* bi = p.b_pri + o * HDI;
#pragma unroll
                for (int i = 0; i < 4; i++) {
                    size_t idx = (size_t)(rb + i) * HDI + ccol;
                    C[idx] = fmaxf(a0[i] + a1[i] + a2[i] + bi[ccol], 0.f);
                }
            }
        }
        gbar(p.bcnt, p.bgen);

        // S2: U_s/U_d GEMM (cat@enc_w) || 4 prior smalls
        for (int u = wg; u < 8192; u += NWAVE) {
            if (u < 4096) {
                int o = u >> 11, w = u & 2047;
                int r = w & 127, cc = w >> 7;
                f32x4 a0 = {}, a1 = {}, a2 = {};
                mmpass(a0, a1, a2, p.phi_xb, NH, p.wt[2 + 2 * o], HDI, r, cc, lr, kg);
                mmpass(a0, a1, a2, h1b16, NH, p.wt[3 + 2 * o], HDI, r, cc, lr, kg);
                int ccol = cc * 16 + lr, rb = r * 16 + (lane >> 4) * 4;
                float* C = o ? p.Ud : p.Us;
#pragma unroll
                for (int i = 0; i < 4; i++)
                    C[(size_t)(rb + i) * HDI + ccol] = a0[i] + a1[i] + a2[i];
            } else {
                int q = u - 4096;
                int s = q >> 10, unit = q & 1023;
                if (s == 0) small2(p.pris, p.w_pm, p.b_pm, p.pms, 0, unit, lane);
                else if (s == 1) small2(p.pris, p.w_ps, p.b_ps, p.pss, 4, unit, lane);
                else if (s == 2) small2(p.prid, p.w_pm + 8192, p.b_pm + 32, p.pmd, 0, unit, lane);
                else small2(p.prid, p.w_ps + 8192, p.b_ps + 32, p.psd, 4, unit, lane);
            }
        }
        gbar(p.bcnt, p.bgen);

        // S3: enc = relu(G(U) + enc_b)
        for (int u = wg; u < 4096; u += NWAVE) {
            int seg = u >> 11, n = u & 2047;
            float4 a = gin_row(seg ? p.Ud : p.Us, n, offs, cs, lane);
            const float* eb = p.b_enc + seg * HDI + c4;
            a.x = fmaxf(a.x + eb[0], 0.f);
            a.y = fmaxf(a.y + eb[1], 0.f);
            a.z = fmaxf(a.z + eb[2], 0.f);
            a.w = fmaxf(a.w + eb[3], 0.f);
            *(float4*)&(seg ? p.encd : p.encs)[(size_t)n * HDI + c4] = a;
        }
        gbar(p.bcnt, p.bgen);

        // S4: xwm / xws smalls
        for (int u = wg; u < 4096; u += NWAVE) {
            int s = u >> 10, unit = u & 1023;
            if (s == 0) small2(p.encs, p.w_mean, nullptr, p.xwms, 0, unit, lane);
            else if (s == 1) small2(p.encd, p.w_mean + 8192, nullptr, p.xwmd, 0, unit, lane);
            else if (s == 2) small2(p.encs, p.w_std, nullptr, p.xwss, 0, unit, lane);
            else small2(p.encd, p.w_std + 8192, nullptr, p.xwsd, 0, unit, lane);
        }
        gbar(p.bcnt, p.bgen);

        // S5: gcn(mean) + gin+softplus(std)
        for (int u = wg; u < 4096; u += NWAVE) {
            int s = u >> 10, unit = u & 1023;
            if (s == 0) gcn2(p.xwms, p.b_mean, p.means, offs, cs, cw, dgv, unit, lane);
            else if (s == 1) gcn2(p.xwmd, p.b_mean + 32, p.meand, offs, cs, cw, dgv, unit, lane);
            else if (s == 2) gin32sp(p.xwss, p.b_std, p.stds, offs, cs, unit, lane);
            else gin32sp(p.xwsd, p.b_std + 32, p.stdd, offs, cs, unit, lane);
        }
        gbar(p.bcnt, p.bgen);

        // S6: z build + KLD (blocks 0..255)
        for (int bu = bid; bu < 256; bu += NBLK) {
            int i = bu * 256 + tid;
            int n = i >> 5, z = i & 31;
            float m1 = p.means[i], s1v = p.stds[i];
            float n1 = p.meand[i], t1v = p.stdd[i];
            float zs = m1 + s1v * es_t[i];
            float zd = n1 + t1v * ed_t[i];
            p.zcat[(size_t)n * 64 + z] = zs;
            p.zcat[(size_t)n * 64 + 32 + z] = zd;
            st_b16(p.zcatb, ZPL, (size_t)n * 64 + z, zs);
            st_b16(p.zcatb, ZPL, (size_t)n * 64 + 32 + z, zd);
            float v;
            {
                float a1 = s1v + EPSC, a2 = p.pss[i] + EPSC;
                float dm = m1 - p.pms[i];
                v = 2.f * (logf(a2) - logf(a1)) + (a1 * a1 + dm * dm) / (a2 * a2) - 1.f;
            }
            {
                float a1 = t1v + EPSC, a2 = p.psd[i] + EPSC;
                float dm = n1 - p.pmd[i];
                v += 2.f * (logf(a2) - logf(a1)) + (a1 * a1 + dm * dm) / (a2 * a2) - 1.f;
            }
            smf[tid] = v;
            __syncthreads();
            for (int o = 128; o > 0; o >>= 1) {
                if (tid < o) smf[tid] += smf[tid + o];
                __syncthreads();
            }
            if (tid == 0) atomicAdd(&p.accd[0], (double)smf[0]);
            __syncthreads();
        }
        gbar(p.bcnt, p.bgen);

        // S7: phi_z GEMM (bf16-out) || dec+BCE (blocks 0..511)
        if (bid < 512) {
            for (int db = bid; db < 1024; db += 512) {
                __syncthreads();
                dec_tile(p.zcat, adj_t, dec_t, acc3, db, tid, smf);
            }
        } else {
            for (int u = (bid - 512) * 4 + wid; u < 2048; u += 2048) {
                int r = u & 127, cc = u >> 7;
                f32x4 a0 = {}, a1 = {}, a2 = {};
                mmpass(a0, a1, a2, p.zcatb, ZPL, p.wt[1], 64, r, cc, lr, kg);
                int ccol = cc * 16 + lr, rb = r * 16 + (lane >> 4) * 4;
#pragma unroll
                for (int i = 0; i < 4; i++) {
                    size_t idx = (size_t)(rb + i) * HDI + ccol;
                    st_b16(p.phi_zb, NH, idx, fmaxf(a0[i] + a1[i] + a2[i], 0.f));
                }
            }
        }
        gbar(p.bcnt, p.bgen);

        // S8: GRU0 P gates: Pz, Pr (3 passes), Ph (2 passes)
        for (int u = wg; u < 6144; u += NWAVE) {
            int o = u >> 11, w = u & 2047;
            int r = w & 127, cc = w >> 7;
            f32x4 a0 = {}, a1 = {}, a2 = {};
            if (o == 0) {
                mmpass(a0, a1, a2, p.phi_xb, NH, p.wt[8], HDI, r, cc, lr, kg);
                mmpass(a0, a1, a2, p.phi_zb, NH, p.wt[9], HDI, r, cc, lr, kg);
                mmpass(a0, a1, a2, h0b16, NH, p.wt[14], HDI, r, cc, lr, kg);
            } else if (o == 1) {
                mmpass(a0, a1, a2, p.phi_xb, NH, p.wt[10], HDI, r, cc, lr, kg);
                mmpass(a0, a1, a2, p.phi_zb, NH, p.wt[11], HDI, r, cc, lr, kg);
                mmpass(a0, a1, a2, h0b16, NH, p.wt[15], HDI, r, cc, lr, kg);
            } else {
                mmpass(a0, a1, a2, p.phi_xb, NH, p.wt[12], HDI, r, cc, lr, kg);
                mmpass(a0, a1, a2, p.phi_zb, NH, p.wt[13], HDI, r, cc, lr, kg);
            }
            int ccol = cc * 16 + lr, rb = r * 16 + (lane >> 4) * 4;
            float* C = (o == 0) ? p.Pz : (o == 1) ? p.Pr : p.Ph;
#pragma unroll
            for (int i = 0; i < 4; i++)
                C[(size_t)(rb + i) * HDI + ccol] = a0[i] + a1[i] + a2[i];
        }
        gbar(p.bcnt, p.bgen);

        // S9: zG = sig(G(Pz)); rh = sig(G(Pr))*h0 -> bf16
        for (int u = wg; u < 4096; u += NWAVE) {
            int seg = u >> 11, n = u & 2047;
            size_t idx = (size_t)n * HDI + c4;
            if (seg == 0) {
                float4 a = gin_row(p.Pz, n, offs, cs, lane);
                a.x = 1.f / (1.f + expf(-a.x)); a.y = 1.f / (1.f + expf(-a.y));
                a.z = 1.f / (1.f + expf(-a.z)); a.w = 1.f / (1.f + expf(-a.w));
                *(float4*)&p.zG[idx] = a;
            } else {
                float4 a = gin_row(p.Pr, n, offs, cs, lane);
                float4 h4 = *(const float4*)&h0[idx];
                float4 rh;
                rh.x = h4.x / (1.f + expf(-a.x)); rh.y = h4.y / (1.f + expf(-a.y));
                rh.z = h4.z / (1.f + expf(-a.z)); rh.w = h4.w / (1.f + expf(-a.w));
                st_b16v4(p.rhb, NH, idx, rh);
            }
        }
        gbar(p.bcnt, p.bgen);

        // S10: R = rh@Whh0 + Ph
        for (int u = wg; u < 2048; u += NWAVE) {
            int r = u & 127, cc = u >> 7;
            f32x4 a0 = {}, a1 = {}, a2 = {};
            mmpass(a0, a1, a2, p.rhb, NH, p.wt[16], HDI, r, cc, lr, kg);
            int ccol = cc * 16 + lr, rb = r * 16 + (lane >> 4) * 4;
#pragma unroll
            for (int i = 0; i < 4; i++) {
                size_t idx = (size_t)(rb + i) * HDI + ccol;
                p.R[idx] = a0[i] + a1[i] + a2[i] + p.Ph[idx];
            }
        }
        gbar(p.bcnt, p.bgen);

        // S11: nh0 = zG*h0 + (1-zG)*tanh(G(R))
        for (int u = wg; u < 2048; u += NWAVE) {
            int n = u;
            size_t idx = (size_t)n * HDI + c4;
            float4 a = gin_row(p.R, n, offs, cs, lane);
            float4 z4 = *(const float4*)&p.zG[idx];
            float4 h4 = *(const float4*)&h0[idx];
            float4 o;
            o.x = z4.x * h4.x + (1.f - z4.x) * tanhf(a.x);
            o.y = z4.y * h4.y + (1.f - z4.y) * tanhf(a.y);
            o.z = z4.z * h4.z + (1.f - z4.z) * tanhf(a.z);
            o.w = z4.w * h4.w + (1.f - z4.w) * tanhf(a.w);
            *(float4*)&nh0[idx] = o;
            st_b16v4(nh0b16, NH, idx, o);
        }
        gbar(p.bcnt, p.bgen);

        // S12: GRU1 P gates
        for (int u = wg; u < 6144; u += NWAVE) {
            int o = u >> 11, w = u & 2047;
            int r = w & 127, cc = w >> 7;
            f32x4 a0 = {}, a1 = {}, a2 = {};
            if (o == 0) {
                mmpass(a0, a1, a2, nh0b16, NH, p.wt[17], HDI, r, cc, lr, kg);
                mmpass(a0, a1, a2, h1b16, NH, p.wt[20], HDI, r, cc, lr, kg);
            } else if (o == 1) {
                mmpass(a0, a1, a2, nh0b16, NH, p.wt[18], HDI, r, cc, lr, kg);
                mmpass(a0, a1, a2, h1b16, NH, p.wt[21], HDI, r, cc, lr, kg);
            } else {
                mmpass(a0, a1, a2, nh0b16, NH, p.wt[19], HDI, r, cc, lr, kg);
            }
            int ccol = cc * 16 + lr, rb = r * 16 + (lane >> 4) * 4;
            float* C = (o == 0) ? p.Pz : (o == 1) ? p.Pr : p.Ph;
#pragma unroll
            for (int i = 0; i < 4; i++)
                C[(size_t)(rb + i) * HDI + ccol] = a0[i] + a1[i] + a2[i];
        }
        gbar(p.bcnt, p.bgen);

        // S13: zG, rh for layer 1
        for (int u = wg; u < 4096; u += NWAVE) {
            int seg = u >> 11, n = u & 2047;
            size_t idx = (size_t)n * HDI + c4;
            if (seg == 0) {
                float4 a = gin_row(p.Pz, n, offs, cs, lane);
                a.x = 1.f / (1.f + expf(-a.x)); a.y = 1.f / (1.f + expf(-a.y));
                a.z = 1.f / (1.f + expf(-a.z)); a.w = 1.f / (1.f + expf(-a.w));
                *(float4*)&p.zG[idx] = a;
            } else {
                float4 a = gin_row(p.Pr, n, offs, cs, lane);
                float4 h4 = *(const float4*)&h1[idx];
                float4 rh;
                rh.x = h4.x / (1.f + expf(-a.x)); rh.y = h4.y / (1.f + expf(-a.y));
                rh.z = h4.z / (1.f + expf(-a.z)); rh.w = h4.w / (1.f + expf(-a.w));
                st_b16v4(p.rhb, NH, idx, rh);
            }
        }
        gbar(p.bcnt, p.bgen);

        // S14: R = rh@Whh1 + Ph
        for (int u = wg; u < 2048; u += NWAVE) {
            int r = u & 127, cc = u >> 7;
            f32x4 a0 = {}, a1 = {}, a2 = {};
            mmpass(a0, a1, a2, p.rhb, NH, p.wt[22], HDI, r, cc, lr, kg);
            int ccol = cc * 16 + lr, rb = r * 16 + (lane >> 4) * 4;
#pragma unroll
            for (int i = 0; i < 4; i++) {
                size_t idx = (size_t)(rb + i) * HDI + ccol;
                p.R[idx] = a0[i] + a1[i] + a2[i] + p.Ph[idx];
            }
        }
        gbar(p.bcnt, p.bgen);

        // S15: nh1 = zG*h1 + (1-zG)*tanh(G(R))
        for (int u = wg; u < 2048; u += NWAVE) {
            int n = u;
            size_t idx = (size_t)n * HDI + c4;
            float4 a = gin_row(p.R, n, offs, cs, lane);
            float4 z4 = *(const float4*)&p.zG[idx];
            float4 h4 = *(const float4*)&h1[idx];
            float4 o;
            o.x = z4.x * h4.x + (1.f - z4.x) * tanhf(a.x);
            o.y = z4.y * h4.y + (1.f - z4.y) * tanhf(a.y);
            o.z = z4.z * h4.z + (1.f - z4.z) * tanhf(a.z);
            o.w = z4.w * h4.w + (1.f - z4.w) * tanhf(a.w);
            *(float4*)&nh1[idx] = o;
            st_b16v4(nh1b16, NH, idx, o);
        }
        gbar(p.bcnt, p.bgen);
    }

    // finalize
    if (bid == 0 && tid == 0) {
        const double nn2 = (double)NND * (double)NND;
        p.out[0] = (float)(0.5 * p.accd[0] / nn2);
        double nll = 0.0;
        for (int t = 0; t < NTS; ++t) {
            double s = p.accd[1 + 3 * t];
            double S1 = p.accd[2 + 3 * t];
            double S2 = p.accd[3 + 3 * t];
            double posw = (nn2 - s) / s;
            double norm = nn2 / ((nn2 - s) * 2.0);
            nll += norm * (-posw * S1 - S2) / nn2;
        }
        p.out[1] = (float)nll;
    }
}

// ---------------- host ----------------

extern "C" void kernel_launch(void* const* d_in, const int* in_sizes, int n_in,
                              void* d_out, int out_size, void* d_ws, size_t ws_size,
                              hipStream_t stream) {
    (void)in_sizes; (void)n_in; (void)out_size; (void)ws_size;

    const float* x_all = (const float*)d_in[0];
    const int* ei_all = (const int*)d_in[1];
    const float* adj_all = (const float*)d_in[2];
    const float* eps_s_all = (const float*)d_in[3];
    const float* eps_d_all = (const float*)d_in[4];
    const float* phi_x_w = (const float*)d_in[5];
    const float* phi_z_w = (const float*)d_in[6];
    const float* gru_xw0 = (const float*)d_in[7];
    const float* gru_xw1 = (const float*)d_in[8];
    const float* gru_hw = (const float*)d_in[9];
    const float* enc_w = (const float*)d_in[10];
    const float* enc_b = (const float*)d_in[11];
    const float* mean_w = (const float*)d_in[12];
    const float* mean_b = (const float*)d_in[13];
    const float* std_w = (const float*)d_in[14];
    const float* std_b = (const float*)d_in[15];
    const float* pri_w = (const float*)d_in[16];
    const float* pri_b = (const float*)d_in[17];
    const float* pri_mw = (const float*)d_in[18];
    const float* pri_mb = (const float*)d_in[19];
    const float* pri_sw = (const float*)d_in[20];
    const float* pri_sb = (const float*)d_in[21];

    size_t off = 0;
    auto alloc = [&](size_t bytes) -> void* {
        void* p = (char*)d_ws + off;
        off = (off + bytes + 255) & ~(size_t)255;
        return p;
    };

    PP p = {};
    p.x = x_all; p.ei = ei_all; p.adj = adj_all; p.es = eps_s_all; p.ed = eps_d_all;
    p.b_enc = enc_b; p.b_pri = pri_b;
    p.w_mean = mean_w; p.b_mean = mean_b; p.w_std = std_w; p.b_std = std_b;
    p.w_pm = pri_mw; p.b_pm = pri_mb; p.w_ps = pri_sw; p.b_ps = pri_sb;
    p.out = (float*)d_out;

    // h state (f32 ping/pong x 2 layers) — zeroed wholesale
    float* hf = (float*)alloc(4 * NH * 4);
    p.h0f[0] = hf; p.h0f[1] = hf + NH; p.h1f[0] = hf + 2 * NH; p.h1f[1] = hf + 3 * NH;
    u16* hb = (u16*)alloc(4 * 2 * NH * 2);
    p.h0b[0] = hb; p.h0b[1] = hb + 2 * NH; p.h1b[0] = hb + 4 * NH; p.h1b[1] = hb + 6 * NH;

    p.xb = (u16*)alloc(2 * XSZ * 2);
    p.phi_xb = (u16*)alloc(2 * NH * 2);
    p.phi_zb = (u16*)alloc(2 * NH * 2);
    p.rhb = (u16*)alloc(2 * NH * 2);
    p.zcatb = (u16*)alloc(2 * ZPL * 2);
    p.Us = (float*)alloc(NH * 4);
    p.Ud = (float*)alloc(NH * 4);
    p.encs = (float*)alloc(NH * 4);
    p.encd = (float*)alloc(NH * 4);
    p.pris = (float*)alloc(NH * 4);
    p.prid = (float*)alloc(NH * 4);
    p.Pz = (float*)alloc(NH * 4);
    p.Pr = (float*)alloc(NH * 4);
    p.Ph = (float*)alloc(NH * 4);
    p.zG = (float*)alloc(NH * 4);
    p.R = (float*)alloc(NH * 4);
    p.xwms = (float*)alloc(NZ * 4);
    p.xwmd = (float*)alloc(NZ * 4);
    p.xwss = (float*)alloc(NZ * 4);
    p.xwsd = (float*)alloc(NZ * 4);
    p.means = (float*)alloc(NZ * 4);
    p.meand = (float*)alloc(NZ * 4);
    p.stds = (float*)alloc(NZ * 4);
    p.stdd = (float*)alloc(NZ * 4);
    p.pms = (float*)alloc(NZ * 4);
    p.pss = (float*)alloc(NZ * 4);
    p.pmd = (float*)alloc(NZ * 4);
    p.psd = (float*)alloc(NZ * 4);
    p.zcat = (float*)alloc((size_t)NND * 64 * 4);
    p.deg = (float*)alloc((size_t)NTS * NND * 4);
    p.dinv = (float*)alloc((size_t)NTS * NND * 4);
    p.counts = (int*)alloc(2 * (size_t)NTS * NND * 4);
    p.cursor = p.counts + (size_t)NTS * NND;
    p.offs = (int*)alloc((size_t)NTS * (NND + 1) * 4);
    p.csrcb = (int*)alloc((size_t)NTS * NED * 4);
    p.csrwb = (float*)alloc((size_t)NTS * NED * 4);
    p.accd = (double*)alloc((1 + 3 * NTS) * 8);
    p.bcnt = (int*)alloc(256);
    p.bgen = (int*)alloc(256);

    // bf16 transposed weights: idx -> (src, K)
    const size_t W66K = 65536;   // 256*256
    const float* wsrc[23] = {
        phi_x_w, phi_z_w,
        enc_w, enc_w + 256 * 256,
        enc_w + 512 * 256, enc_w + 512 * 256 + 256 * 256,
        pri_w, pri_w + W66K,
        gru_xw0, gru_xw0 + W66K,
        gru_xw0 + 2 * W66K, gru_xw0 + 3 * W66K,
        gru_xw0 + 4 * W66K, gru_xw0 + 5 * W66K,
        gru_hw, gru_hw + W66K, gru_hw + 2 * W66K,
        gru_xw1, gru_xw1 + W66K, gru_xw1 + 2 * W66K,
        gru_hw + 3 * W66K, gru_hw + 4 * W66K, gru_hw + 5 * W66K};
    int wk[23];
    for (int m = 0; m < 23; m++) wk[m] = 256;
    wk[0] = XDI; wk[1] = 64;
    for (int m = 0; m < 23; m++) {
        p.wt[m] = (u16*)alloc((size_t)wk[m] * HDI * 2 * 2);
        p.wsrc[m] = wsrc[m];
        p.wk[m] = wk[m];
    }

    hipMemsetAsync(hf, 0, 4 * NH * 4, stream);
    hipMemsetAsync(hb, 0, 4 * 2 * NH * 2, stream);
    hipMemsetAsync(p.counts, 0, 2 * (size_t)NTS * NND * 4, stream);
    hipMemsetAsync(p.accd, 0, (1 + 3 * NTS) * 8, stream);
    hipMemsetAsync(p.bcnt, 0, 512, stream);   // bcnt + bgen (adjacent 256B slots)

    mega<<<NBLK, 256, 0, stream>>>(p);
}